// Round 1
// baseline (1737.453 us; speedup 1.0000x reference)
//
#include <hip/hip_runtime.h>
#include <hip/hip_bf16.h>

#define NVV 100000
#define NCC 400000
#define NEE 1600000

typedef short short8 __attribute__((ext_vector_type(8)));
typedef short short4v __attribute__((ext_vector_type(4)));
typedef float f32x4 __attribute__((ext_vector_type(4)));

__device__ __forceinline__ float b2f(short s) {
    unsigned int u = ((unsigned int)(unsigned short)s) << 16;
    return __builtin_bit_cast(float, u);
}
__device__ __forceinline__ short f2b(float f) {
    __hip_bfloat16 h = __float2bfloat16(f);
    return __builtin_bit_cast(short, h);
}

// ---------------- weight prep: W [nmat, K, 128] f32 -> WT [nmat, 128, K] bf16 ----------------
__global__ __launch_bounds__(256)
void prep_w(const float* __restrict__ W, short* __restrict__ WT, int K, int tot)
{
    int e = blockIdx.x * 256 + threadIdx.x;
    if (e >= tot) return;
    int mk = e >> 7;          // mi*K + k
    int n = e & 127;
    int mi = mk / K;
    int k = mk - mi * K;
    WT[(size_t)mi * K * 128 + (size_t)n * K + k] = f2b(W[e]);
}

// ---------------- fused pos/neg message MLP ----------------
// X f32 [M,128]; weights pre-transposed bf16 W^T[n][k] (two sets, stride 16384).
// Z gets set-0 output at Z, set-1 at Z + zstr. Transposed MFMA compute as before:
// A = W^T fragments (direct from global/L2), B = X row fragments.
template<int BM>
__global__ __launch_bounds__(BM * 2, 3)
void mlp2_msg(const float* __restrict__ X,
              const short* __restrict__ W1T, const float* __restrict__ B1,
              const short* __restrict__ W2T, const float* __restrict__ B2,
              short* __restrict__ Z, size_t zstr, int M)
{
    __shared__ short sH[BM * 136];
    const int tid = threadIdx.x;
    const int lane = tid & 63;
    const int w = tid >> 6;
    const int p = lane & 15;
    const int q = lane >> 4;
    const long rowBase = (long)blockIdx.x * BM;

    long mrow[2]; int rowok[2];
    #pragma unroll
    for (int t = 0; t < 2; ++t) {
        long m = rowBase + w * 32 + t * 16 + p;
        rowok[t] = (m < (long)M);
        mrow[t] = (m <= (long)M - 1) ? m : (long)M - 1;
    }

    // load X fragments once (reused by both weight sets)
    short8 xf[2][4];
    #pragma unroll
    for (int t = 0; t < 2; ++t) {
        #pragma unroll
        for (int kk = 0; kk < 4; ++kk) {
            const float* src = X + mrow[t] * 128 + kk * 32 + q * 8;
            f32x4 a = *(const f32x4*)(src);
            f32x4 b = *(const f32x4*)(src + 4);
            short8 sv;
            #pragma unroll
            for (int j = 0; j < 4; ++j) { sv[j] = f2b(a[j]); sv[j + 4] = f2b(b[j]); }
            xf[t][kk] = sv;
        }
    }

    for (int s = 0; s < 2; ++s) {
        const short* w1 = W1T + s * 16384;
        f32x4 acc[8][2];
        #pragma unroll
        for (int c = 0; c < 8; ++c)
            #pragma unroll
            for (int t = 0; t < 2; ++t)
                acc[c][t] = (f32x4){0.f, 0.f, 0.f, 0.f};

        #pragma unroll
        for (int kk = 0; kk < 4; ++kk) {
            short8 af[8];
            #pragma unroll
            for (int c = 0; c < 8; ++c)
                af[c] = *(const short8*)(w1 + (c * 16 + p) * 128 + kk * 32 + q * 8);
            #pragma unroll
            for (int c = 0; c < 8; ++c)
                #pragma unroll
                for (int t = 0; t < 2; ++t)
                    acc[c][t] = __builtin_amdgcn_mfma_f32_16x16x32_bf16(af[c], xf[t][kk], acc[c][t], 0, 0, 0);
        }

        #pragma unroll
        for (int c = 0; c < 8; ++c) {
            f32x4 bb = *(const f32x4*)(B1 + s * 128 + c * 16 + q * 4);
            #pragma unroll
            for (int t = 0; t < 2; ++t) {
                short4v sv;
                #pragma unroll
                for (int i = 0; i < 4; ++i)
                    sv[i] = f2b(fmaxf(acc[c][t][i] + bb[i], 0.f));
                *(short4v*)(sH + (w * 32 + t * 16 + p) * 136 + c * 16 + q * 4) = sv;
            }
        }
        __syncthreads();

        const short* w2 = W2T + s * 16384;
        f32x4 acc2[8][2];
        #pragma unroll
        for (int c = 0; c < 8; ++c)
            #pragma unroll
            for (int t = 0; t < 2; ++t)
                acc2[c][t] = (f32x4){0.f, 0.f, 0.f, 0.f};

        #pragma unroll
        for (int kk = 0; kk < 4; ++kk) {
            short8 af[8], bfr[2];
            #pragma unroll
            for (int c = 0; c < 8; ++c)
                af[c] = *(const short8*)(w2 + (c * 16 + p) * 128 + kk * 32 + q * 8);
            #pragma unroll
            for (int t = 0; t < 2; ++t)
                bfr[t] = *(const short8*)(sH + (w * 32 + t * 16 + p) * 136 + kk * 32 + q * 8);
            #pragma unroll
            for (int c = 0; c < 8; ++c)
                #pragma unroll
                for (int t = 0; t < 2; ++t)
                    acc2[c][t] = __builtin_amdgcn_mfma_f32_16x16x32_bf16(af[c], bfr[t], acc2[c][t], 0, 0, 0);
        }

        short* z = Z + (size_t)s * zstr;
        #pragma unroll
        for (int c = 0; c < 8; ++c) {
            f32x4 bb = *(const f32x4*)(B2 + s * 128 + c * 16 + q * 4);
            #pragma unroll
            for (int t = 0; t < 2; ++t) {
                if (rowok[t]) {
                    long row = rowBase + w * 32 + t * 16 + p;
                    short4v sv;
                    #pragma unroll
                    for (int i = 0; i < 4; ++i)
                        sv[i] = f2b(fmaxf(acc2[c][t][i] + bb[i], 0.f));
                    *(short4v*)(z + row * 128 + c * 16 + q * 4) = sv;
                }
            }
        }
        if (s == 0) __syncthreads();
    }
}

// ---------------- update MLP: X = concat(h f32, m bf16), K1=256; weights direct from global ----------------
template<int BM>
__global__ __launch_bounds__(BM * 2, 3)
void mlp2_upd(const float* __restrict__ X, const short* __restrict__ X2,
              const short* __restrict__ W1T, const float* __restrict__ B1,
              const short* __restrict__ W2T, const float* __restrict__ B2,
              float* __restrict__ Out, int M)
{
    __shared__ short sH[BM * 136];
    const int tid = threadIdx.x;
    const int lane = tid & 63;
    const int w = tid >> 6;
    const int p = lane & 15;
    const int q = lane >> 4;
    const long rowBase = (long)blockIdx.x * BM;

    long mrow[2]; int rowok[2];
    #pragma unroll
    for (int t = 0; t < 2; ++t) {
        long m = rowBase + w * 32 + t * 16 + p;
        rowok[t] = (m < (long)M);
        mrow[t] = (m <= (long)M - 1) ? m : (long)M - 1;
    }

    f32x4 acc[8][2];
    #pragma unroll
    for (int c = 0; c < 8; ++c)
        #pragma unroll
        for (int t = 0; t < 2; ++t)
            acc[c][t] = (f32x4){0.f, 0.f, 0.f, 0.f};

    #pragma unroll
    for (int kk = 0; kk < 8; ++kk) {
        short8 xf[2];
        const int k0 = kk * 32 + q * 8;
        #pragma unroll
        for (int t = 0; t < 2; ++t) {
            if (kk >= 4) {
                xf[t] = *(const short8*)(X2 + mrow[t] * 128 + (k0 - 128));
            } else {
                const float* src = X + mrow[t] * 128 + k0;
                f32x4 a = *(const f32x4*)(src);
                f32x4 b = *(const f32x4*)(src + 4);
                short8 sv;
                #pragma unroll
                for (int j = 0; j < 4; ++j) { sv[j] = f2b(a[j]); sv[j + 4] = f2b(b[j]); }
                xf[t] = sv;
            }
        }
        short8 af[8];
        #pragma unroll
        for (int c = 0; c < 8; ++c)
            af[c] = *(const short8*)(W1T + (c * 16 + p) * 256 + kk * 32 + q * 8);
        #pragma unroll
        for (int c = 0; c < 8; ++c)
            #pragma unroll
            for (int t = 0; t < 2; ++t)
                acc[c][t] = __builtin_amdgcn_mfma_f32_16x16x32_bf16(af[c], xf[t], acc[c][t], 0, 0, 0);
    }

    #pragma unroll
    for (int c = 0; c < 8; ++c) {
        f32x4 bb = *(const f32x4*)(B1 + c * 16 + q * 4);
        #pragma unroll
        for (int t = 0; t < 2; ++t) {
            short4v sv;
            #pragma unroll
            for (int i = 0; i < 4; ++i)
                sv[i] = f2b(fmaxf(acc[c][t][i] + bb[i], 0.f));
            *(short4v*)(sH + (w * 32 + t * 16 + p) * 136 + c * 16 + q * 4) = sv;
        }
    }
    __syncthreads();

    f32x4 acc2[8][2];
    #pragma unroll
    for (int c = 0; c < 8; ++c)
        #pragma unroll
        for (int t = 0; t < 2; ++t)
            acc2[c][t] = (f32x4){0.f, 0.f, 0.f, 0.f};

    #pragma unroll
    for (int kk = 0; kk < 4; ++kk) {
        short8 af[8], bfr[2];
        #pragma unroll
        for (int c = 0; c < 8; ++c)
            af[c] = *(const short8*)(W2T + (c * 16 + p) * 128 + kk * 32 + q * 8);
        #pragma unroll
        for (int t = 0; t < 2; ++t)
            bfr[t] = *(const short8*)(sH + (w * 32 + t * 16 + p) * 136 + kk * 32 + q * 8);
        #pragma unroll
        for (int c = 0; c < 8; ++c)
            #pragma unroll
            for (int t = 0; t < 2; ++t)
                acc2[c][t] = __builtin_amdgcn_mfma_f32_16x16x32_bf16(af[c], bfr[t], acc2[c][t], 0, 0, 0);
    }

    #pragma unroll
    for (int c = 0; c < 8; ++c) {
        f32x4 bb = *(const f32x4*)(B2 + c * 16 + q * 4);
        #pragma unroll
        for (int t = 0; t < 2; ++t) {
            if (rowok[t]) {
                long row = rowBase + w * 32 + t * 16 + p;
                f32x4 fv;
                #pragma unroll
                for (int i = 0; i < 4; ++i)
                    fv[i] = fmaxf(acc2[c][t][i] + bb[i], 0.f);
                *(f32x4*)(Out + row * 128 + c * 16 + q * 4) = fv;
            }
        }
    }
}

// ---------------- CSR build ----------------

__global__ __launch_bounds__(256)
void hist_kernel(const int* __restrict__ rows, int* __restrict__ counts, int E)
{
    int e = blockIdx.x * 256 + threadIdx.x;
    if (e < E) atomicAdd(&counts[rows[e]], 1);
}

__global__ __launch_bounds__(256)
void seg_reduce(const int* __restrict__ counts, int* __restrict__ bsum, int N)
{
    __shared__ int s[256];
    int b = blockIdx.x, t = threadIdx.x;
    int base = b * 512;
    int v = 0;
    if (base + t < N) v += counts[base + t];
    if (base + 256 + t < N) v += counts[base + 256 + t];
    s[t] = v;
    __syncthreads();
    for (int off = 128; off > 0; off >>= 1) {
        if (t < off) s[t] += s[t + off];
        __syncthreads();
    }
    if (t == 0) bsum[b] = s[0];
}

__global__ __launch_bounds__(1024)
void scan_bsum(int* __restrict__ bsum, int B)
{
    __shared__ int s[1024];
    int t = threadIdx.x;
    s[t] = (t < B) ? bsum[t] : 0;
    __syncthreads();
    for (int off = 1; off < 1024; off <<= 1) {
        int v = (t >= off) ? s[t - off] : 0;
        __syncthreads();
        s[t] += v;
        __syncthreads();
    }
    if (t < B) bsum[t] = (t == 0) ? 0 : s[t - 1];
}

__global__ __launch_bounds__(512)
void scan_final(const int* __restrict__ counts, const int* __restrict__ bsum,
                int* __restrict__ offs, int N)
{
    __shared__ int s[512];
    int b = blockIdx.x, t = threadIdx.x;
    int idx = b * 512 + t;
    int c = (idx < N) ? counts[idx] : 0;
    s[t] = c;
    __syncthreads();
    for (int off = 1; off < 512; off <<= 1) {
        int v = (t >= off) ? s[t - off] : 0;
        __syncthreads();
        s[t] += v;
        __syncthreads();
    }
    if (idx < N) offs[idx] = bsum[b] + s[t] - c;
    if (idx == N - 1) offs[N] = bsum[b] + s[t];
}

__global__ __launch_bounds__(256)
void csr_fill(const int* __restrict__ rows, const int* __restrict__ cols,
              const int* __restrict__ offs, int* __restrict__ cursor,
              int* __restrict__ edgeCol, int E)
{
    int e = blockIdx.x * 256 + threadIdx.x;
    if (e >= E) return;
    int r = rows[e];
    int pos = offs[r] + atomicAdd(&cursor[r], 1);
    edgeCol[pos] = cols[e];
}

__global__ __launch_bounds__(256)
void csr_gather(const short* __restrict__ z, const int* __restrict__ offs,
                const int* __restrict__ edgeCol, short* __restrict__ m, int N)
{
    int wave = (int)((blockIdx.x * 256 + threadIdx.x) >> 6);
    int lane = threadIdx.x & 63;
    if (wave >= N) return;
    int beg = offs[wave], end = offs[wave + 1];
    float a0 = 0.f, a1 = 0.f;
    int j = beg;
    for (; j + 1 < end; j += 2) {
        int c0 = edgeCol[j], c1 = edgeCol[j + 1];
        unsigned int v0 = *(const unsigned int*)(z + (long)c0 * 128 + lane * 2);
        unsigned int v1 = *(const unsigned int*)(z + (long)c1 * 128 + lane * 2);
        a0 += b2f((short)(v0 & 0xffff)) + b2f((short)(v1 & 0xffff));
        a1 += b2f((short)(v0 >> 16)) + b2f((short)(v1 >> 16));
    }
    if (j < end) {
        int c = edgeCol[j];
        unsigned int v = *(const unsigned int*)(z + (long)c * 128 + lane * 2);
        a0 += b2f((short)(v & 0xffff));
        a1 += b2f((short)(v >> 16));
    }
    unsigned int o = ((unsigned int)(unsigned short)f2b(a1) << 16) | (unsigned short)f2b(a0);
    *(unsigned int*)(m + (long)wave * 128 + lane * 2) = o;
}

extern "C" void kernel_launch(void* const* d_in, const int* in_sizes, int n_in,
                              void* d_out, int out_size, void* d_ws, size_t ws_size,
                              hipStream_t stream)
{
    const float* hv   = (const float*)d_in[0];
    const float* hc   = (const float*)d_in[1];
    const int* row_v  = (const int*)d_in[2];
    const int* col_v  = (const int*)d_in[3];
    const int* row_c  = (const int*)d_in[4];
    const int* col_c  = (const int*)d_in[5];
    const float* mw1  = (const float*)d_in[6];
    const float* mb1  = (const float*)d_in[7];
    const float* mw2  = (const float*)d_in[8];
    const float* mb2  = (const float*)d_in[9];
    const float* uw1  = (const float*)d_in[10];
    const float* ub1  = (const float*)d_in[11];
    const float* uw2  = (const float*)d_in[12];
    const float* ub2  = (const float*)d_in[13];
    float* out = (float*)d_out;

    // ws: zv bf16[2NC,128] | zc bf16[2NV,128] | mv bf16[NV,128] | mc bf16[NC,128]
    //     | WT bf16 (mw1,mw2,uw1,uw2 transposed) | int scratch
    short* zv = (short*)d_ws;
    short* zc = zv + (size_t)2 * NCC * 128;
    short* mv = zc + (size_t)2 * NVV * 128;
    short* mc = mv + (size_t)NVV * 128;
    short* wt_m1 = mc + (size_t)NCC * 128;      // 4 * 16384
    short* wt_m2 = wt_m1 + 4 * 16384;           // 4 * 16384
    short* wt_u1 = wt_m2 + 4 * 16384;           // 2 * 32768
    short* wt_u2 = wt_u1 + 2 * 32768;           // 2 * 16384
    int* edge_v = (int*)(wt_u2 + 2 * 16384);
    int* edge_c = edge_v + NEE;
    int* offs_v = edge_c + NEE;
    int* offs_c = offs_v + (NVV + 1);
    int* cnt_v  = offs_c + (NCC + 1);
    int* cnt_c  = cnt_v + NVV;
    int* bsum_v = cnt_c + NCC;
    int* bsum_c = bsum_v + 1024;

    const int Bv = (NVV + 511) / 512;   // 196
    const int Bc = (NCC + 511) / 512;   // 782

    // ---- weight prep (tiny)
    prep_w<<<(4 * 16384 + 255) / 256, 256, 0, stream>>>(mw1, wt_m1, 128, 4 * 16384);
    prep_w<<<(4 * 16384 + 255) / 256, 256, 0, stream>>>(mw2, wt_m2, 128, 4 * 16384);
    prep_w<<<(2 * 32768 + 255) / 256, 256, 0, stream>>>(uw1, wt_u1, 256, 2 * 32768);
    prep_w<<<(2 * 16384 + 255) / 256, 256, 0, stream>>>(uw2, wt_u2, 128, 2 * 16384);

    // ---- CSR build (both graphs)
    hipMemsetAsync(cnt_v, 0, NVV * sizeof(int), stream);
    hipMemsetAsync(cnt_c, 0, NCC * sizeof(int), stream);
    hist_kernel<<<(NEE + 255) / 256, 256, 0, stream>>>(row_v, cnt_v, NEE);
    hist_kernel<<<(NEE + 255) / 256, 256, 0, stream>>>(row_c, cnt_c, NEE);
    seg_reduce<<<Bv, 256, 0, stream>>>(cnt_v, bsum_v, NVV);
    seg_reduce<<<Bc, 256, 0, stream>>>(cnt_c, bsum_c, NCC);
    scan_bsum<<<1, 1024, 0, stream>>>(bsum_v, Bv);
    scan_bsum<<<1, 1024, 0, stream>>>(bsum_c, Bc);
    scan_final<<<Bv, 512, 0, stream>>>(cnt_v, bsum_v, offs_v, NVV);
    scan_final<<<Bc, 512, 0, stream>>>(cnt_c, bsum_c, offs_c, NCC);
    hipMemsetAsync(cnt_v, 0, NVV * sizeof(int), stream);
    hipMemsetAsync(cnt_c, 0, NCC * sizeof(int), stream);
    csr_fill<<<(NEE + 255) / 256, 256, 0, stream>>>(row_v, col_v, offs_v, cnt_v, edge_v, NEE);
    csr_fill<<<(NEE + 255) / 256, 256, 0, stream>>>(row_c, col_c, offs_c, cnt_c, edge_c, NEE);

    // ---- fused message MLPs: zv = [fmv_pos(hc); fmv_neg(hc)] (sets 0,1), zc = [fmc_pos(hv); fmc_neg(hv)] (sets 2,3)
    mlp2_msg<128><<<NCC / 128, 256, 0, stream>>>(
        hc, wt_m1, mb1, wt_m2, mb2, zv, (size_t)NCC * 128, NCC);
    mlp2_msg<128><<<(NVV + 127) / 128, 256, 0, stream>>>(
        hv, wt_m1 + 2 * 16384, mb1 + 2 * 128, wt_m2 + 2 * 16384, mb2 + 2 * 128,
        zc, (size_t)NVV * 128, NVV);

    // ---- segment sums via CSR gather
    csr_gather<<<(NVV + 3) / 4, 256, 0, stream>>>(zv, offs_v, edge_v, mv, NVV);
    csr_gather<<<(NCC + 3) / 4, 256, 0, stream>>>(zc, offs_c, edge_c, mc, NCC);

    // ---- update MLPs: concat(h, m) -> K1=256
    mlp2_upd<256><<<(NVV + 255) / 256, 512, 0, stream>>>(
        hv, mv, wt_u1, ub1, wt_u2, ub2, out, NVV);
    mlp2_upd<256><<<(NCC + 255) / 256, 512, 0, stream>>>(
        hc, mc, wt_u1 + 32768, ub1 + 128, wt_u2 + 16384, ub2 + 128,
        out + (size_t)NVV * 128, NCC);
}

// Round 2
// 1396.410 us; speedup vs baseline: 1.2442x; 1.2442x over previous
//
#include <hip/hip_runtime.h>
#include <hip/hip_bf16.h>

#define NVV 100000
#define NCC 400000
#define NEE 1600000

typedef short short8 __attribute__((ext_vector_type(8)));
typedef short short4v __attribute__((ext_vector_type(4)));
typedef float f32x4 __attribute__((ext_vector_type(4)));

__device__ __forceinline__ float b2f(short s) {
    unsigned int u = ((unsigned int)(unsigned short)s) << 16;
    return __builtin_bit_cast(float, u);
}
__device__ __forceinline__ short f2b(float f) {
    __hip_bfloat16 h = __float2bfloat16(f);
    return __builtin_bit_cast(short, h);
}

// ---------------- weight prep: W [nmat, K, 128] f32 -> WT [nmat, 128, K] bf16 ----------------
__global__ __launch_bounds__(256)
void prep_w(const float* __restrict__ W, short* __restrict__ WT, int K, int tot)
{
    int e = blockIdx.x * 256 + threadIdx.x;
    if (e >= tot) return;
    int mk = e >> 7;          // mi*K + k
    int n = e & 127;
    int mi = mk / K;
    int k = mk - mi * K;
    WT[(size_t)mi * K * 128 + (size_t)n * K + k] = f2b(W[e]);
}

// ---------------- weight-stationary message MLP (persistent blocks) ----------------
// One weight set per block (set = blockIdx.x & 1). Weights staged to LDS once,
// then grid-stride over BM-row chunks. sH is wave-private -> no barriers in loop.
template<int NW>
__global__ __launch_bounds__(NW * 64, 1)
void mlp2_msg_ws(const float* __restrict__ X,
                 const short* __restrict__ W1T, const float* __restrict__ B1,
                 const short* __restrict__ W2T, const float* __restrict__ B2,
                 short* __restrict__ Z, size_t zstr, int M, int nChunks)
{
    constexpr int BM = NW * 32;
    constexpr int NT = NW * 64;
    __shared__ short sW1[128 * 136];
    __shared__ short sW2[128 * 136];
    __shared__ short sH[BM * 136];

    const int tid = threadIdx.x;
    const int lane = tid & 63;
    const int w = tid >> 6;
    const int p = lane & 15;
    const int q = lane >> 4;

    const int set = blockIdx.x & 1;
    const int c0 = blockIdx.x >> 1;
    const int cstr = gridDim.x >> 1;

    const short* w1g = W1T + set * 16384;
    const short* w2g = W2T + set * 16384;
    const float* b1g = B1 + set * 128;
    const float* b2g = B2 + set * 128;
    short* z = Z + (size_t)set * zstr;

    // stage weights once (padded rows: stride 136 shorts = 272B, conflict-free-ish reads)
    for (int e = tid * 8; e < 128 * 128; e += NT * 8) {
        int n = e >> 7, k = e & 127;
        *(short8*)(sW1 + n * 136 + k) = *(const short8*)(w1g + e);
        *(short8*)(sW2 + n * 136 + k) = *(const short8*)(w2g + e);
    }
    __syncthreads();

    if (c0 >= nChunks) return;

    f32x4 ra[2][4], rb[2][4];
    auto issueX = [&](int c) {
        long base = (long)c * BM + w * 32;
        #pragma unroll
        for (int t = 0; t < 2; ++t) {
            long m = base + t * 16 + p;
            if (m > (long)M - 1) m = (long)M - 1;
            const float* src = X + m * 128 + q * 8;
            #pragma unroll
            for (int kk = 0; kk < 4; ++kk) {
                ra[t][kk] = *(const f32x4*)(src + kk * 32);
                rb[t][kk] = *(const f32x4*)(src + kk * 32 + 4);
            }
        }
    };
    issueX(c0);

    for (int c = c0; c < nChunks; c += cstr) {
        // convert current chunk's X to bf16 fragments, then immediately issue next prefetch
        short8 xf[2][4];
        #pragma unroll
        for (int t = 0; t < 2; ++t)
            #pragma unroll
            for (int kk = 0; kk < 4; ++kk) {
                short8 s8;
                #pragma unroll
                for (int j = 0; j < 4; ++j) { s8[j] = f2b(ra[t][kk][j]); s8[j + 4] = f2b(rb[t][kk][j]); }
                xf[t][kk] = s8;
            }
        if (c + cstr < nChunks) issueX(c + cstr);

        // layer 1
        f32x4 acc[8][2];
        #pragma unroll
        for (int cc = 0; cc < 8; ++cc)
            #pragma unroll
            for (int t = 0; t < 2; ++t)
                acc[cc][t] = (f32x4){0.f, 0.f, 0.f, 0.f};

        #pragma unroll
        for (int kk = 0; kk < 4; ++kk) {
            short8 af[8];
            #pragma unroll
            for (int cc = 0; cc < 8; ++cc)
                af[cc] = *(const short8*)(sW1 + (cc * 16 + p) * 136 + kk * 32 + q * 8);
            #pragma unroll
            for (int cc = 0; cc < 8; ++cc)
                #pragma unroll
                for (int t = 0; t < 2; ++t)
                    acc[cc][t] = __builtin_amdgcn_mfma_f32_16x16x32_bf16(af[cc], xf[t][kk], acc[cc][t], 0, 0, 0);
        }

        #pragma unroll
        for (int cc = 0; cc < 8; ++cc) {
            f32x4 bb = *(const f32x4*)(b1g + cc * 16 + q * 4);
            #pragma unroll
            for (int t = 0; t < 2; ++t) {
                short4v sv;
                #pragma unroll
                for (int i = 0; i < 4; ++i)
                    sv[i] = f2b(fmaxf(acc[cc][t][i] + bb[i], 0.f));
                *(short4v*)(sH + (w * 32 + t * 16 + p) * 136 + cc * 16 + q * 4) = sv;
            }
        }
        // wave-private sH: only need this wave's LDS writes complete before reads
        asm volatile("s_waitcnt lgkmcnt(0)" ::: "memory");

        // layer 2
        f32x4 acc2[8][2];
        #pragma unroll
        for (int cc = 0; cc < 8; ++cc)
            #pragma unroll
            for (int t = 0; t < 2; ++t)
                acc2[cc][t] = (f32x4){0.f, 0.f, 0.f, 0.f};

        #pragma unroll
        for (int kk = 0; kk < 4; ++kk) {
            short8 af[8], bfr[2];
            #pragma unroll
            for (int cc = 0; cc < 8; ++cc)
                af[cc] = *(const short8*)(sW2 + (cc * 16 + p) * 136 + kk * 32 + q * 8);
            #pragma unroll
            for (int t = 0; t < 2; ++t)
                bfr[t] = *(const short8*)(sH + (w * 32 + t * 16 + p) * 136 + kk * 32 + q * 8);
            #pragma unroll
            for (int cc = 0; cc < 8; ++cc)
                #pragma unroll
                for (int t = 0; t < 2; ++t)
                    acc2[cc][t] = __builtin_amdgcn_mfma_f32_16x16x32_bf16(af[cc], bfr[t], acc2[cc][t], 0, 0, 0);
        }

        long base = (long)c * BM + w * 32;
        #pragma unroll
        for (int cc = 0; cc < 8; ++cc) {
            f32x4 bb = *(const f32x4*)(b2g + cc * 16 + q * 4);
            #pragma unroll
            for (int t = 0; t < 2; ++t) {
                long m = base + t * 16 + p;
                if (m < M) {
                    short4v sv;
                    #pragma unroll
                    for (int i = 0; i < 4; ++i)
                        sv[i] = f2b(fmaxf(acc2[cc][t][i] + bb[i], 0.f));
                    *(short4v*)(z + m * 128 + cc * 16 + q * 4) = sv;
                }
            }
        }
    }
}

// ---------------- weight-stationary update MLP: X = concat(h f32, m bf16), K1=256 ----------------
template<int NW>
__global__ __launch_bounds__(NW * 64, 1)
void mlp2_upd_ws(const float* __restrict__ X, const short* __restrict__ X2,
                 const short* __restrict__ W1T, const float* __restrict__ B1,
                 const short* __restrict__ W2T, const float* __restrict__ B2,
                 float* __restrict__ Out, int M, int nChunks)
{
    constexpr int BM = NW * 32;
    constexpr int NT = NW * 64;
    __shared__ short sW1[128 * 264];   // K=256, pad 8
    __shared__ short sW2[128 * 136];
    __shared__ short sH[BM * 136];

    const int tid = threadIdx.x;
    const int lane = tid & 63;
    const int w = tid >> 6;
    const int p = lane & 15;
    const int q = lane >> 4;

    const int c0 = blockIdx.x;
    const int cstr = gridDim.x;

    for (int e = tid * 8; e < 128 * 256; e += NT * 8) {
        int n = e >> 8, k = e & 255;
        *(short8*)(sW1 + n * 264 + k) = *(const short8*)(W1T + e);
    }
    for (int e = tid * 8; e < 128 * 128; e += NT * 8) {
        int n = e >> 7, k = e & 127;
        *(short8*)(sW2 + n * 136 + k) = *(const short8*)(W2T + e);
    }
    __syncthreads();

    if (c0 >= nChunks) return;

    f32x4 ra[2][4], rb[2][4];
    short8 rx2[2][4];
    auto issueXf = [&](int c) {
        long base = (long)c * BM + w * 32;
        #pragma unroll
        for (int t = 0; t < 2; ++t) {
            long m = base + t * 16 + p;
            if (m > (long)M - 1) m = (long)M - 1;
            const float* src = X + m * 128 + q * 8;
            #pragma unroll
            for (int kk = 0; kk < 4; ++kk) {
                ra[t][kk] = *(const f32x4*)(src + kk * 32);
                rb[t][kk] = *(const f32x4*)(src + kk * 32 + 4);
            }
        }
    };
    auto issueX2 = [&](int c) {
        long base = (long)c * BM + w * 32;
        #pragma unroll
        for (int t = 0; t < 2; ++t) {
            long m = base + t * 16 + p;
            if (m > (long)M - 1) m = (long)M - 1;
            const short* src = X2 + m * 128 + q * 8;
            #pragma unroll
            for (int kk = 0; kk < 4; ++kk)
                rx2[t][kk] = *(const short8*)(src + kk * 32);
        }
    };
    issueXf(c0);
    issueX2(c0);

    for (int c = c0; c < nChunks; c += cstr) {
        short8 xf1[2][4];
        #pragma unroll
        for (int t = 0; t < 2; ++t)
            #pragma unroll
            for (int kk = 0; kk < 4; ++kk) {
                short8 s8;
                #pragma unroll
                for (int j = 0; j < 4; ++j) { s8[j] = f2b(ra[t][kk][j]); s8[j + 4] = f2b(rb[t][kk][j]); }
                xf1[t][kk] = s8;
            }
        if (c + cstr < nChunks) issueXf(c + cstr);

        f32x4 acc[8][2];
        #pragma unroll
        for (int cc = 0; cc < 8; ++cc)
            #pragma unroll
            for (int t = 0; t < 2; ++t)
                acc[cc][t] = (f32x4){0.f, 0.f, 0.f, 0.f};

        #pragma unroll
        for (int kk = 0; kk < 8; ++kk) {
            short8 af[8];
            #pragma unroll
            for (int cc = 0; cc < 8; ++cc)
                af[cc] = *(const short8*)(sW1 + (cc * 16 + p) * 264 + kk * 32 + q * 8);
            #pragma unroll
            for (int cc = 0; cc < 8; ++cc)
                #pragma unroll
                for (int t = 0; t < 2; ++t) {
                    short8 xcur = (kk < 4) ? xf1[t][kk] : rx2[t][kk - 4];
                    acc[cc][t] = __builtin_amdgcn_mfma_f32_16x16x32_bf16(af[cc], xcur, acc[cc][t], 0, 0, 0);
                }
        }
        if (c + cstr < nChunks) issueX2(c + cstr);

        #pragma unroll
        for (int cc = 0; cc < 8; ++cc) {
            f32x4 bb = *(const f32x4*)(B1 + cc * 16 + q * 4);
            #pragma unroll
            for (int t = 0; t < 2; ++t) {
                short4v sv;
                #pragma unroll
                for (int i = 0; i < 4; ++i)
                    sv[i] = f2b(fmaxf(acc[cc][t][i] + bb[i], 0.f));
                *(short4v*)(sH + (w * 32 + t * 16 + p) * 136 + cc * 16 + q * 4) = sv;
            }
        }
        asm volatile("s_waitcnt lgkmcnt(0)" ::: "memory");

        f32x4 acc2[8][2];
        #pragma unroll
        for (int cc = 0; cc < 8; ++cc)
            #pragma unroll
            for (int t = 0; t < 2; ++t)
                acc2[cc][t] = (f32x4){0.f, 0.f, 0.f, 0.f};

        #pragma unroll
        for (int kk = 0; kk < 4; ++kk) {
            short8 af[8], bfr[2];
            #pragma unroll
            for (int cc = 0; cc < 8; ++cc)
                af[cc] = *(const short8*)(sW2 + (cc * 16 + p) * 136 + kk * 32 + q * 8);
            #pragma unroll
            for (int t = 0; t < 2; ++t)
                bfr[t] = *(const short8*)(sH + (w * 32 + t * 16 + p) * 136 + kk * 32 + q * 8);
            #pragma unroll
            for (int cc = 0; cc < 8; ++cc)
                #pragma unroll
                for (int t = 0; t < 2; ++t)
                    acc2[cc][t] = __builtin_amdgcn_mfma_f32_16x16x32_bf16(af[cc], bfr[t], acc2[cc][t], 0, 0, 0);
        }

        long base = (long)c * BM + w * 32;
        #pragma unroll
        for (int cc = 0; cc < 8; ++cc) {
            f32x4 bb = *(const f32x4*)(B2 + cc * 16 + q * 4);
            #pragma unroll
            for (int t = 0; t < 2; ++t) {
                long m = base + t * 16 + p;
                if (m < M) {
                    f32x4 fv;
                    #pragma unroll
                    for (int i = 0; i < 4; ++i)
                        fv[i] = fmaxf(acc2[cc][t][i] + bb[i], 0.f);
                    *(f32x4*)(Out + m * 128 + cc * 16 + q * 4) = fv;
                }
            }
        }
    }
}

// ---------------- CSR build ----------------

__global__ __launch_bounds__(256)
void hist_kernel(const int* __restrict__ rows, int* __restrict__ counts, int E)
{
    int e = blockIdx.x * 256 + threadIdx.x;
    if (e < E) atomicAdd(&counts[rows[e]], 1);
}

__global__ __launch_bounds__(256)
void seg_reduce(const int* __restrict__ counts, int* __restrict__ bsum, int N)
{
    __shared__ int s[256];
    int b = blockIdx.x, t = threadIdx.x;
    int base = b * 512;
    int v = 0;
    if (base + t < N) v += counts[base + t];
    if (base + 256 + t < N) v += counts[base + 256 + t];
    s[t] = v;
    __syncthreads();
    for (int off = 128; off > 0; off >>= 1) {
        if (t < off) s[t] += s[t + off];
        __syncthreads();
    }
    if (t == 0) bsum[b] = s[0];
}

__global__ __launch_bounds__(1024)
void scan_bsum(int* __restrict__ bsum, int B)
{
    __shared__ int s[1024];
    int t = threadIdx.x;
    s[t] = (t < B) ? bsum[t] : 0;
    __syncthreads();
    for (int off = 1; off < 1024; off <<= 1) {
        int v = (t >= off) ? s[t - off] : 0;
        __syncthreads();
        s[t] += v;
        __syncthreads();
    }
    if (t < B) bsum[t] = (t == 0) ? 0 : s[t - 1];
}

__global__ __launch_bounds__(512)
void scan_final(const int* __restrict__ counts, const int* __restrict__ bsum,
                int* __restrict__ offs, int N)
{
    __shared__ int s[512];
    int b = blockIdx.x, t = threadIdx.x;
    int idx = b * 512 + t;
    int c = (idx < N) ? counts[idx] : 0;
    s[t] = c;
    __syncthreads();
    for (int off = 1; off < 512; off <<= 1) {
        int v = (t >= off) ? s[t - off] : 0;
        __syncthreads();
        s[t] += v;
        __syncthreads();
    }
    if (idx < N) offs[idx] = bsum[b] + s[t] - c;
    if (idx == N - 1) offs[N] = bsum[b] + s[t];
}

__global__ __launch_bounds__(256)
void csr_fill(const int* __restrict__ rows, const int* __restrict__ cols,
              const int* __restrict__ offs, int* __restrict__ cursor,
              int* __restrict__ edgeCol, int E)
{
    int e = blockIdx.x * 256 + threadIdx.x;
    if (e >= E) return;
    int r = rows[e];
    int pos = offs[r] + atomicAdd(&cursor[r], 1);
    edgeCol[pos] = cols[e];
}

__global__ __launch_bounds__(256)
void csr_gather(const short* __restrict__ z, const int* __restrict__ offs,
                const int* __restrict__ edgeCol, short* __restrict__ m, int N)
{
    int wave = (int)((blockIdx.x * 256 + threadIdx.x) >> 6);
    int lane = threadIdx.x & 63;
    if (wave >= N) return;
    int beg = offs[wave], end = offs[wave + 1];
    float a0 = 0.f, a1 = 0.f;
    int j = beg;
    for (; j + 1 < end; j += 2) {
        int c0 = edgeCol[j], c1 = edgeCol[j + 1];
        unsigned int v0 = *(const unsigned int*)(z + (long)c0 * 128 + lane * 2);
        unsigned int v1 = *(const unsigned int*)(z + (long)c1 * 128 + lane * 2);
        a0 += b2f((short)(v0 & 0xffff)) + b2f((short)(v1 & 0xffff));
        a1 += b2f((short)(v0 >> 16)) + b2f((short)(v1 >> 16));
    }
    if (j < end) {
        int c = edgeCol[j];
        unsigned int v = *(const unsigned int*)(z + (long)c * 128 + lane * 2);
        a0 += b2f((short)(v & 0xffff));
        a1 += b2f((short)(v >> 16));
    }
    unsigned int o = ((unsigned int)(unsigned short)f2b(a1) << 16) | (unsigned short)f2b(a0);
    *(unsigned int*)(m + (long)wave * 128 + lane * 2) = o;
}

extern "C" void kernel_launch(void* const* d_in, const int* in_sizes, int n_in,
                              void* d_out, int out_size, void* d_ws, size_t ws_size,
                              hipStream_t stream)
{
    const float* hv   = (const float*)d_in[0];
    const float* hc   = (const float*)d_in[1];
    const int* row_v  = (const int*)d_in[2];
    const int* col_v  = (const int*)d_in[3];
    const int* row_c  = (const int*)d_in[4];
    const int* col_c  = (const int*)d_in[5];
    const float* mw1  = (const float*)d_in[6];
    const float* mb1  = (const float*)d_in[7];
    const float* mw2  = (const float*)d_in[8];
    const float* mb2  = (const float*)d_in[9];
    const float* uw1  = (const float*)d_in[10];
    const float* ub1  = (const float*)d_in[11];
    const float* uw2  = (const float*)d_in[12];
    const float* ub2  = (const float*)d_in[13];
    float* out = (float*)d_out;

    // ws: zv bf16[2NC,128] | zc bf16[2NV,128] | mv bf16[NV,128] | mc bf16[NC,128]
    //     | WT bf16 (mw1,mw2,uw1,uw2 transposed) | int scratch
    short* zv = (short*)d_ws;
    short* zc = zv + (size_t)2 * NCC * 128;
    short* mv = zc + (size_t)2 * NVV * 128;
    short* mc = mv + (size_t)NVV * 128;
    short* wt_m1 = mc + (size_t)NCC * 128;      // 4 * 16384
    short* wt_m2 = wt_m1 + 4 * 16384;           // 4 * 16384
    short* wt_u1 = wt_m2 + 4 * 16384;           // 2 * 32768
    short* wt_u2 = wt_u1 + 2 * 32768;           // 2 * 16384
    int* edge_v = (int*)(wt_u2 + 2 * 16384);
    int* edge_c = edge_v + NEE;
    int* offs_v = edge_c + NEE;
    int* offs_c = offs_v + (NVV + 1);
    int* cnt_v  = offs_c + (NCC + 1);
    int* cnt_c  = cnt_v + NVV;
    int* bsum_v = cnt_c + NCC;
    int* bsum_c = bsum_v + 1024;

    const int Bv = (NVV + 511) / 512;   // 196
    const int Bc = (NCC + 511) / 512;   // 782

    // ---- weight prep (tiny)
    prep_w<<<(4 * 16384 + 255) / 256, 256, 0, stream>>>(mw1, wt_m1, 128, 4 * 16384);
    prep_w<<<(4 * 16384 + 255) / 256, 256, 0, stream>>>(mw2, wt_m2, 128, 4 * 16384);
    prep_w<<<(2 * 32768 + 255) / 256, 256, 0, stream>>>(uw1, wt_u1, 256, 2 * 32768);
    prep_w<<<(2 * 16384 + 255) / 256, 256, 0, stream>>>(uw2, wt_u2, 128, 2 * 16384);

    // ---- CSR build (both graphs)
    hipMemsetAsync(cnt_v, 0, NVV * sizeof(int), stream);
    hipMemsetAsync(cnt_c, 0, NCC * sizeof(int), stream);
    hist_kernel<<<(NEE + 255) / 256, 256, 0, stream>>>(row_v, cnt_v, NEE);
    hist_kernel<<<(NEE + 255) / 256, 256, 0, stream>>>(row_c, cnt_c, NEE);
    seg_reduce<<<Bv, 256, 0, stream>>>(cnt_v, bsum_v, NVV);
    seg_reduce<<<Bc, 256, 0, stream>>>(cnt_c, bsum_c, NCC);
    scan_bsum<<<1, 1024, 0, stream>>>(bsum_v, Bv);
    scan_bsum<<<1, 1024, 0, stream>>>(bsum_c, Bc);
    scan_final<<<Bv, 512, 0, stream>>>(cnt_v, bsum_v, offs_v, NVV);
    scan_final<<<Bc, 512, 0, stream>>>(cnt_c, bsum_c, offs_c, NCC);
    hipMemsetAsync(cnt_v, 0, NVV * sizeof(int), stream);
    hipMemsetAsync(cnt_c, 0, NCC * sizeof(int), stream);
    csr_fill<<<(NEE + 255) / 256, 256, 0, stream>>>(row_v, col_v, offs_v, cnt_v, edge_v, NEE);
    csr_fill<<<(NEE + 255) / 256, 256, 0, stream>>>(row_c, col_c, offs_c, cnt_c, edge_c, NEE);

    // ---- message MLPs (weight-stationary persistent; set = blockIdx&1)
    mlp2_msg_ws<8><<<512, 512, 0, stream>>>(
        hc, wt_m1, mb1, wt_m2, mb2, zv, (size_t)NCC * 128, NCC, (NCC + 255) / 256);
    mlp2_msg_ws<8><<<512, 512, 0, stream>>>(
        hv, wt_m1 + 2 * 16384, mb1 + 2 * 128, wt_m2 + 2 * 16384, mb2 + 2 * 128,
        zc, (size_t)NVV * 128, NVV, (NVV + 255) / 256);

    // ---- segment sums via CSR gather
    csr_gather<<<(NVV + 3) / 4, 256, 0, stream>>>(zv, offs_v, edge_v, mv, NVV);
    csr_gather<<<(NCC + 3) / 4, 256, 0, stream>>>(zc, offs_c, edge_c, mc, NCC);

    // ---- update MLPs: concat(h, m) -> K1=256
    mlp2_upd_ws<6><<<256, 384, 0, stream>>>(
        hv, mv, wt_u1, ub1, wt_u2, ub2, out, NVV, (NVV + 191) / 192);
    mlp2_upd_ws<6><<<256, 384, 0, stream>>>(
        hc, mc, wt_u1 + 32768, ub1 + 128, wt_u2 + 16384, ub2 + 128,
        out + (size_t)NVV * 128, NCC, (NCC + 191) / 192);
}

// Round 3
// 1388.028 us; speedup vs baseline: 1.2517x; 1.0060x over previous
//
#include <hip/hip_runtime.h>
#include <hip/hip_bf16.h>

#define NVV 100000
#define NCC 400000
#define NEE 1600000

typedef short short8 __attribute__((ext_vector_type(8)));
typedef short short4v __attribute__((ext_vector_type(4)));
typedef float f32x4 __attribute__((ext_vector_type(4)));
typedef unsigned int u32x2 __attribute__((ext_vector_type(2)));
typedef unsigned int u32x4 __attribute__((ext_vector_type(4)));

__device__ __forceinline__ float b2f(short s) {
    unsigned int u = ((unsigned int)(unsigned short)s) << 16;
    return __builtin_bit_cast(float, u);
}
__device__ __forceinline__ short f2b(float f) {
    __hip_bfloat16 h = __float2bfloat16(f);
    return __builtin_bit_cast(short, h);
}
// packed f32->bf16 (RTNE), 2 elements per instruction
__device__ __forceinline__ unsigned int cvtpk(float a, float b) {
    unsigned int r;
    asm("v_cvt_pk_bf16_f32 %0, %1, %2" : "=v"(r) : "v"(a), "v"(b));
    return r;
}

// ---------------- f32 -> bf16 streaming convert ----------------
__global__ __launch_bounds__(256)
void to_bf16(const float* __restrict__ in, short* __restrict__ outp, long n)
{
    long i0 = ((long)blockIdx.x * 256 + threadIdx.x) * 8;
    long stride = (long)gridDim.x * 256 * 8;
    for (long i = i0; i < n; i += stride) {
        f32x4 a = *(const f32x4*)(in + i);
        f32x4 b = *(const f32x4*)(in + i + 4);
        u32x4 o;
        o[0] = cvtpk(a[0], a[1]);
        o[1] = cvtpk(a[2], a[3]);
        o[2] = cvtpk(b[0], b[1]);
        o[3] = cvtpk(b[2], b[3]);
        *(u32x4*)(outp + i) = o;
    }
}

// ---------------- weight prep: W [nmat, K, 128] f32 -> WT [nmat, 128, K] bf16 ----------------
__global__ __launch_bounds__(256)
void prep_w(const float* __restrict__ W, short* __restrict__ WT, int K, int tot)
{
    int e = blockIdx.x * 256 + threadIdx.x;
    if (e >= tot) return;
    int mk = e >> 7;          // mi*K + k
    int n = e & 127;
    int mi = mk / K;
    int k = mk - mi * K;
    WT[(size_t)mi * K * 128 + (size_t)n * K + k] = f2b(W[e]);
}

// ---------------- weight-stationary message MLP (persistent blocks, bf16 X) ----------------
template<int NW>
__global__ __launch_bounds__(NW * 64, 1)
void mlp2_msg_ws(const short* __restrict__ Xb,
                 const short* __restrict__ W1T, const float* __restrict__ B1,
                 const short* __restrict__ W2T, const float* __restrict__ B2,
                 short* __restrict__ Z, size_t zstr, int M, int nChunks)
{
    constexpr int BM = NW * 32;
    constexpr int NT = NW * 64;
    __shared__ short sW1[128 * 136];
    __shared__ short sW2[128 * 136];
    __shared__ short sH[BM * 136];

    const int tid = threadIdx.x;
    const int lane = tid & 63;
    const int w = tid >> 6;
    const int p = lane & 15;
    const int q = lane >> 4;

    const int set = blockIdx.x & 1;
    const int c0 = blockIdx.x >> 1;
    const int cstr = gridDim.x >> 1;

    const short* w1g = W1T + set * 16384;
    const short* w2g = W2T + set * 16384;
    const float* b1g = B1 + set * 128;
    const float* b2g = B2 + set * 128;
    short* z = Z + (size_t)set * zstr;

    for (int e = tid * 8; e < 128 * 128; e += NT * 8) {
        int n = e >> 7, k = e & 127;
        *(short8*)(sW1 + n * 136 + k) = *(const short8*)(w1g + e);
        *(short8*)(sW2 + n * 136 + k) = *(const short8*)(w2g + e);
    }
    __syncthreads();

    if (c0 >= nChunks) return;

    short8 xfA[2][4], xfB[2][4];

    auto issueX = [&](short8 (&xf)[2][4], int c) {
        long base = (long)c * BM + w * 32;
        #pragma unroll
        for (int t = 0; t < 2; ++t) {
            long m = base + t * 16 + p;
            if (m > (long)M - 1) m = (long)M - 1;
            const short* src = Xb + m * 128 + q * 8;
            #pragma unroll
            for (int kk = 0; kk < 4; ++kk)
                xf[t][kk] = *(const short8*)(src + kk * 32);
        }
    };

    auto computeStore = [&](short8 (&xf)[2][4], int c) {
        long base = (long)c * BM + w * 32;
        // layer 1
        f32x4 acc[8][2];
        #pragma unroll
        for (int cc = 0; cc < 8; ++cc)
            #pragma unroll
            for (int t = 0; t < 2; ++t)
                acc[cc][t] = (f32x4){0.f, 0.f, 0.f, 0.f};

        #pragma unroll
        for (int kk = 0; kk < 4; ++kk) {
            short8 af[8];
            #pragma unroll
            for (int cc = 0; cc < 8; ++cc)
                af[cc] = *(const short8*)(sW1 + (cc * 16 + p) * 136 + kk * 32 + q * 8);
            #pragma unroll
            for (int cc = 0; cc < 8; ++cc)
                #pragma unroll
                for (int t = 0; t < 2; ++t)
                    acc[cc][t] = __builtin_amdgcn_mfma_f32_16x16x32_bf16(af[cc], xf[t][kk], acc[cc][t], 0, 0, 0);
        }

        #pragma unroll
        for (int cc = 0; cc < 8; ++cc) {
            f32x4 bb = *(const f32x4*)(b1g + cc * 16 + q * 4);
            #pragma unroll
            for (int t = 0; t < 2; ++t) {
                u32x2 u;
                u[0] = cvtpk(fmaxf(acc[cc][t][0] + bb[0], 0.f), fmaxf(acc[cc][t][1] + bb[1], 0.f));
                u[1] = cvtpk(fmaxf(acc[cc][t][2] + bb[2], 0.f), fmaxf(acc[cc][t][3] + bb[3], 0.f));
                *(u32x2*)(sH + (w * 32 + t * 16 + p) * 136 + cc * 16 + q * 4) = u;
            }
        }
        // wave-private sH: just drain this wave's LDS writes
        asm volatile("s_waitcnt lgkmcnt(0)" ::: "memory");

        // layer 2
        f32x4 acc2[8][2];
        #pragma unroll
        for (int cc = 0; cc < 8; ++cc)
            #pragma unroll
            for (int t = 0; t < 2; ++t)
                acc2[cc][t] = (f32x4){0.f, 0.f, 0.f, 0.f};

        #pragma unroll
        for (int kk = 0; kk < 4; ++kk) {
            short8 af[8], bfr[2];
            #pragma unroll
            for (int cc = 0; cc < 8; ++cc)
                af[cc] = *(const short8*)(sW2 + (cc * 16 + p) * 136 + kk * 32 + q * 8);
            #pragma unroll
            for (int t = 0; t < 2; ++t)
                bfr[t] = *(const short8*)(sH + (w * 32 + t * 16 + p) * 136 + kk * 32 + q * 8);
            #pragma unroll
            for (int cc = 0; cc < 8; ++cc)
                #pragma unroll
                for (int t = 0; t < 2; ++t)
                    acc2[cc][t] = __builtin_amdgcn_mfma_f32_16x16x32_bf16(af[cc], bfr[t], acc2[cc][t], 0, 0, 0);
        }

        #pragma unroll
        for (int cc = 0; cc < 8; ++cc) {
            f32x4 bb = *(const f32x4*)(b2g + cc * 16 + q * 4);
            #pragma unroll
            for (int t = 0; t < 2; ++t) {
                long m = base + t * 16 + p;
                if (m < M) {
                    u32x2 u;
                    u[0] = cvtpk(fmaxf(acc2[cc][t][0] + bb[0], 0.f), fmaxf(acc2[cc][t][1] + bb[1], 0.f));
                    u[1] = cvtpk(fmaxf(acc2[cc][t][2] + bb[2], 0.f), fmaxf(acc2[cc][t][3] + bb[3], 0.f));
                    *(u32x2*)(z + m * 128 + cc * 16 + q * 4) = u;
                }
            }
        }
    };

    int c = c0;
    issueX(xfA, c);
    while (true) {
        if (c + cstr < nChunks) issueX(xfB, c + cstr);
        computeStore(xfA, c);
        c += cstr; if (c >= nChunks) break;
        if (c + cstr < nChunks) issueX(xfA, c + cstr);
        computeStore(xfB, c);
        c += cstr; if (c >= nChunks) break;
    }
}

// ---------------- weight-stationary update MLP: X = concat(h bf16, m bf16), K1=256 ----------------
template<int NW>
__global__ __launch_bounds__(NW * 64, 1)
void mlp2_upd_ws(const short* __restrict__ Xb, const short* __restrict__ X2,
                 const short* __restrict__ W1T, const float* __restrict__ B1,
                 const short* __restrict__ W2T, const float* __restrict__ B2,
                 float* __restrict__ Out, int M, int nChunks)
{
    constexpr int BM = NW * 32;
    constexpr int NT = NW * 64;
    __shared__ short sW1[128 * 264];   // K=256, pad 8
    __shared__ short sW2[128 * 136];
    __shared__ short sH[BM * 136];

    const int tid = threadIdx.x;
    const int lane = tid & 63;
    const int w = tid >> 6;
    const int p = lane & 15;
    const int q = lane >> 4;

    const int c0 = blockIdx.x;
    const int cstr = gridDim.x;

    for (int e = tid * 8; e < 128 * 256; e += NT * 8) {
        int n = e >> 8, k = e & 255;
        *(short8*)(sW1 + n * 264 + k) = *(const short8*)(W1T + e);
    }
    for (int e = tid * 8; e < 128 * 128; e += NT * 8) {
        int n = e >> 7, k = e & 127;
        *(short8*)(sW2 + n * 136 + k) = *(const short8*)(W2T + e);
    }
    __syncthreads();

    if (c0 >= nChunks) return;

    short8 bufA[2][8], bufB[2][8];   // [t][kk] over K=256

    auto issueX = [&](short8 (&xf)[2][8], int c) {
        long base = (long)c * BM + w * 32;
        #pragma unroll
        for (int t = 0; t < 2; ++t) {
            long m = base + t * 16 + p;
            if (m > (long)M - 1) m = (long)M - 1;
            const short* s1 = Xb + m * 128 + q * 8;
            const short* s2 = X2 + m * 128 + q * 8;
            #pragma unroll
            for (int kk = 0; kk < 4; ++kk) {
                xf[t][kk]     = *(const short8*)(s1 + kk * 32);
                xf[t][kk + 4] = *(const short8*)(s2 + kk * 32);
            }
        }
    };

    auto computeStore = [&](short8 (&xf)[2][8], int c) {
        long base = (long)c * BM + w * 32;
        f32x4 acc[8][2];
        #pragma unroll
        for (int cc = 0; cc < 8; ++cc)
            #pragma unroll
            for (int t = 0; t < 2; ++t)
                acc[cc][t] = (f32x4){0.f, 0.f, 0.f, 0.f};

        #pragma unroll
        for (int kk = 0; kk < 8; ++kk) {
            short8 af[8];
            #pragma unroll
            for (int cc = 0; cc < 8; ++cc)
                af[cc] = *(const short8*)(sW1 + (cc * 16 + p) * 264 + kk * 32 + q * 8);
            #pragma unroll
            for (int cc = 0; cc < 8; ++cc)
                #pragma unroll
                for (int t = 0; t < 2; ++t)
                    acc[cc][t] = __builtin_amdgcn_mfma_f32_16x16x32_bf16(af[cc], xf[t][kk], acc[cc][t], 0, 0, 0);
        }

        #pragma unroll
        for (int cc = 0; cc < 8; ++cc) {
            f32x4 bb = *(const f32x4*)(B1 + cc * 16 + q * 4);
            #pragma unroll
            for (int t = 0; t < 2; ++t) {
                u32x2 u;
                u[0] = cvtpk(fmaxf(acc[cc][t][0] + bb[0], 0.f), fmaxf(acc[cc][t][1] + bb[1], 0.f));
                u[1] = cvtpk(fmaxf(acc[cc][t][2] + bb[2], 0.f), fmaxf(acc[cc][t][3] + bb[3], 0.f));
                *(u32x2*)(sH + (w * 32 + t * 16 + p) * 136 + cc * 16 + q * 4) = u;
            }
        }
        asm volatile("s_waitcnt lgkmcnt(0)" ::: "memory");

        f32x4 acc2[8][2];
        #pragma unroll
        for (int cc = 0; cc < 8; ++cc)
            #pragma unroll
            for (int t = 0; t < 2; ++t)
                acc2[cc][t] = (f32x4){0.f, 0.f, 0.f, 0.f};

        #pragma unroll
        for (int kk = 0; kk < 4; ++kk) {
            short8 af[8], bfr[2];
            #pragma unroll
            for (int cc = 0; cc < 8; ++cc)
                af[cc] = *(const short8*)(sW2 + (cc * 16 + p) * 136 + kk * 32 + q * 8);
            #pragma unroll
            for (int t = 0; t < 2; ++t)
                bfr[t] = *(const short8*)(sH + (w * 32 + t * 16 + p) * 136 + kk * 32 + q * 8);
            #pragma unroll
            for (int cc = 0; cc < 8; ++cc)
                #pragma unroll
                for (int t = 0; t < 2; ++t)
                    acc2[cc][t] = __builtin_amdgcn_mfma_f32_16x16x32_bf16(af[cc], bfr[t], acc2[cc][t], 0, 0, 0);
        }

        #pragma unroll
        for (int cc = 0; cc < 8; ++cc) {
            f32x4 bb = *(const f32x4*)(B2 + cc * 16 + q * 4);
            #pragma unroll
            for (int t = 0; t < 2; ++t) {
                long m = base + t * 16 + p;
                if (m < M) {
                    f32x4 fv;
                    #pragma unroll
                    for (int i = 0; i < 4; ++i)
                        fv[i] = fmaxf(acc2[cc][t][i] + bb[i], 0.f);
                    *(f32x4*)(Out + m * 128 + cc * 16 + q * 4) = fv;
                }
            }
        }
    };

    int c = c0;
    issueX(bufA, c);
    while (true) {
        if (c + cstr < nChunks) issueX(bufB, c + cstr);
        computeStore(bufA, c);
        c += cstr; if (c >= nChunks) break;
        if (c + cstr < nChunks) issueX(bufA, c + cstr);
        computeStore(bufB, c);
        c += cstr; if (c >= nChunks) break;
    }
}

// ---------------- CSR build ----------------

__global__ __launch_bounds__(256)
void hist_kernel(const int* __restrict__ rows, int* __restrict__ counts, int E)
{
    int e = blockIdx.x * 256 + threadIdx.x;
    if (e < E) atomicAdd(&counts[rows[e]], 1);
}

__global__ __launch_bounds__(256)
void seg_reduce(const int* __restrict__ counts, int* __restrict__ bsum, int N)
{
    __shared__ int s[256];
    int b = blockIdx.x, t = threadIdx.x;
    int base = b * 512;
    int v = 0;
    if (base + t < N) v += counts[base + t];
    if (base + 256 + t < N) v += counts[base + 256 + t];
    s[t] = v;
    __syncthreads();
    for (int off = 128; off > 0; off >>= 1) {
        if (t < off) s[t] += s[t + off];
        __syncthreads();
    }
    if (t == 0) bsum[b] = s[0];
}

__global__ __launch_bounds__(1024)
void scan_bsum(int* __restrict__ bsum, int B)
{
    __shared__ int s[1024];
    int t = threadIdx.x;
    s[t] = (t < B) ? bsum[t] : 0;
    __syncthreads();
    for (int off = 1; off < 1024; off <<= 1) {
        int v = (t >= off) ? s[t - off] : 0;
        __syncthreads();
        s[t] += v;
        __syncthreads();
    }
    if (t < B) bsum[t] = (t == 0) ? 0 : s[t - 1];
}

__global__ __launch_bounds__(512)
void scan_final(const int* __restrict__ counts, const int* __restrict__ bsum,
                int* __restrict__ offs, int N)
{
    __shared__ int s[512];
    int b = blockIdx.x, t = threadIdx.x;
    int idx = b * 512 + t;
    int c = (idx < N) ? counts[idx] : 0;
    s[t] = c;
    __syncthreads();
    for (int off = 1; off < 512; off <<= 1) {
        int v = (t >= off) ? s[t - off] : 0;
        __syncthreads();
        s[t] += v;
        __syncthreads();
    }
    if (idx < N) offs[idx] = bsum[b] + s[t] - c;
    if (idx == N - 1) offs[N] = bsum[b] + s[t];
}

__global__ __launch_bounds__(256)
void csr_fill(const int* __restrict__ rows, const int* __restrict__ cols,
              const int* __restrict__ offs, int* __restrict__ cursor,
              int* __restrict__ edgeCol, int E)
{
    int e = blockIdx.x * 256 + threadIdx.x;
    if (e >= E) return;
    int r = rows[e];
    int pos = offs[r] + atomicAdd(&cursor[r], 1);
    edgeCol[pos] = cols[e];
}

__global__ __launch_bounds__(256)
void csr_gather(const short* __restrict__ z, const int* __restrict__ offs,
                const int* __restrict__ edgeCol, short* __restrict__ m, int N)
{
    int wave = (int)((blockIdx.x * 256 + threadIdx.x) >> 6);
    int lane = threadIdx.x & 63;
    if (wave >= N) return;
    int beg = offs[wave], end = offs[wave + 1];
    float a0 = 0.f, a1 = 0.f;
    int j = beg;
    for (; j + 1 < end; j += 2) {
        int c0 = edgeCol[j], c1 = edgeCol[j + 1];
        unsigned int v0 = *(const unsigned int*)(z + (long)c0 * 128 + lane * 2);
        unsigned int v1 = *(const unsigned int*)(z + (long)c1 * 128 + lane * 2);
        a0 += b2f((short)(v0 & 0xffff)) + b2f((short)(v1 & 0xffff));
        a1 += b2f((short)(v0 >> 16)) + b2f((short)(v1 >> 16));
    }
    if (j < end) {
        int c = edgeCol[j];
        unsigned int v = *(const unsigned int*)(z + (long)c * 128 + lane * 2);
        a0 += b2f((short)(v & 0xffff));
        a1 += b2f((short)(v >> 16));
    }
    unsigned int o = cvtpk(a0, a1);
    *(unsigned int*)(m + (long)wave * 128 + lane * 2) = o;
}

extern "C" void kernel_launch(void* const* d_in, const int* in_sizes, int n_in,
                              void* d_out, int out_size, void* d_ws, size_t ws_size,
                              hipStream_t stream)
{
    const float* hv   = (const float*)d_in[0];
    const float* hc   = (const float*)d_in[1];
    const int* row_v  = (const int*)d_in[2];
    const int* col_v  = (const int*)d_in[3];
    const int* row_c  = (const int*)d_in[4];
    const int* col_c  = (const int*)d_in[5];
    const float* mw1  = (const float*)d_in[6];
    const float* mb1  = (const float*)d_in[7];
    const float* mw2  = (const float*)d_in[8];
    const float* mb2  = (const float*)d_in[9];
    const float* uw1  = (const float*)d_in[10];
    const float* ub1  = (const float*)d_in[11];
    const float* uw2  = (const float*)d_in[12];
    const float* ub2  = (const float*)d_in[13];
    float* out = (float*)d_out;

    // ws: zv bf16[2NC,128] | zc bf16[2NV,128] | mv bf16[NV,128] | mc bf16[NC,128]
    //     | WT bf16 | hvb bf16[NV,128] | hcb bf16[NC,128] | int scratch
    short* zv = (short*)d_ws;
    short* zc = zv + (size_t)2 * NCC * 128;
    short* mv = zc + (size_t)2 * NVV * 128;
    short* mc = mv + (size_t)NVV * 128;
    short* wt_m1 = mc + (size_t)NCC * 128;      // 4 * 16384
    short* wt_m2 = wt_m1 + 4 * 16384;           // 4 * 16384
    short* wt_u1 = wt_m2 + 4 * 16384;           // 2 * 32768
    short* wt_u2 = wt_u1 + 2 * 32768;           // 2 * 16384
    short* hvb = wt_u2 + 2 * 16384;
    short* hcb = hvb + (size_t)NVV * 128;
    int* edge_v = (int*)(hcb + (size_t)NCC * 128);
    int* edge_c = edge_v + NEE;
    int* offs_v = edge_c + NEE;
    int* offs_c = offs_v + (NVV + 1);
    int* cnt_v  = offs_c + (NCC + 1);
    int* cnt_c  = cnt_v + NVV;
    int* bsum_v = cnt_c + NCC;
    int* bsum_c = bsum_v + 1024;

    const int Bv = (NVV + 511) / 512;   // 196
    const int Bc = (NCC + 511) / 512;   // 782

    // ---- weight prep + input bf16 conversion
    prep_w<<<(4 * 16384 + 255) / 256, 256, 0, stream>>>(mw1, wt_m1, 128, 4 * 16384);
    prep_w<<<(4 * 16384 + 255) / 256, 256, 0, stream>>>(mw2, wt_m2, 128, 4 * 16384);
    prep_w<<<(2 * 32768 + 255) / 256, 256, 0, stream>>>(uw1, wt_u1, 256, 2 * 32768);
    prep_w<<<(2 * 16384 + 255) / 256, 256, 0, stream>>>(uw2, wt_u2, 128, 2 * 16384);
    to_bf16<<<2048, 256, 0, stream>>>(hv, hvb, (long)NVV * 128);
    to_bf16<<<2048, 256, 0, stream>>>(hc, hcb, (long)NCC * 128);

    // ---- CSR build (both graphs)
    hipMemsetAsync(cnt_v, 0, NVV * sizeof(int), stream);
    hipMemsetAsync(cnt_c, 0, NCC * sizeof(int), stream);
    hist_kernel<<<(NEE + 255) / 256, 256, 0, stream>>>(row_v, cnt_v, NEE);
    hist_kernel<<<(NEE + 255) / 256, 256, 0, stream>>>(row_c, cnt_c, NEE);
    seg_reduce<<<Bv, 256, 0, stream>>>(cnt_v, bsum_v, NVV);
    seg_reduce<<<Bc, 256, 0, stream>>>(cnt_c, bsum_c, NCC);
    scan_bsum<<<1, 1024, 0, stream>>>(bsum_v, Bv);
    scan_bsum<<<1, 1024, 0, stream>>>(bsum_c, Bc);
    scan_final<<<Bv, 512, 0, stream>>>(cnt_v, bsum_v, offs_v, NVV);
    scan_final<<<Bc, 512, 0, stream>>>(cnt_c, bsum_c, offs_c, NCC);
    hipMemsetAsync(cnt_v, 0, NVV * sizeof(int), stream);
    hipMemsetAsync(cnt_c, 0, NCC * sizeof(int), stream);
    csr_fill<<<(NEE + 255) / 256, 256, 0, stream>>>(row_v, col_v, offs_v, cnt_v, edge_v, NEE);
    csr_fill<<<(NEE + 255) / 256, 256, 0, stream>>>(row_c, col_c, offs_c, cnt_c, edge_c, NEE);

    // ---- message MLPs (weight-stationary persistent; set = blockIdx&1)
    mlp2_msg_ws<8><<<256, 512, 0, stream>>>(
        hcb, wt_m1, mb1, wt_m2, mb2, zv, (size_t)NCC * 128, NCC, (NCC + 255) / 256);
    mlp2_msg_ws<8><<<256, 512, 0, stream>>>(
        hvb, wt_m1 + 2 * 16384, mb1 + 2 * 128, wt_m2 + 2 * 16384, mb2 + 2 * 128,
        zc, (size_t)NVV * 128, NVV, (NVV + 255) / 256);

    // ---- segment sums via CSR gather
    csr_gather<<<(NVV + 3) / 4, 256, 0, stream>>>(zv, offs_v, edge_v, mv, NVV);
    csr_gather<<<(NCC + 3) / 4, 256, 0, stream>>>(zc, offs_c, edge_c, mc, NCC);

    // ---- update MLPs: concat(h, m) -> K1=256
    mlp2_upd_ws<6><<<256, 384, 0, stream>>>(
        hvb, mv, wt_u1, ub1, wt_u2, ub2, out, NVV, (NVV + 191) / 192);
    mlp2_upd_ws<6><<<256, 384, 0, stream>>>(
        hcb, mc, wt_u1 + 32768, ub1 + 128, wt_u2 + 16384, ub2 + 128,
        out + (size_t)NVV * 128, NCC, (NCC + 191) / 192);
}

// Round 4
// 1244.794 us; speedup vs baseline: 1.3958x; 1.1151x over previous
//
#include <hip/hip_runtime.h>
#include <hip/hip_bf16.h>

#define NVV 100000
#define NCC 400000
#define NEE 1600000

typedef short short8 __attribute__((ext_vector_type(8)));
typedef short short4v __attribute__((ext_vector_type(4)));
typedef float f32x4 __attribute__((ext_vector_type(4)));
typedef unsigned int u32x2 __attribute__((ext_vector_type(2)));
typedef unsigned int u32x4 __attribute__((ext_vector_type(4)));

__device__ __forceinline__ float b2f(short s) {
    unsigned int u = ((unsigned int)(unsigned short)s) << 16;
    return __builtin_bit_cast(float, u);
}
__device__ __forceinline__ short f2b(float f) {
    __hip_bfloat16 h = __float2bfloat16(f);
    return __builtin_bit_cast(short, h);
}
// packed f32->bf16 (RTNE), 2 elements per instruction
__device__ __forceinline__ unsigned int cvtpk(float a, float b) {
    unsigned int r;
    asm("v_cvt_pk_bf16_f32 %0, %1, %2" : "=v"(r) : "v"(a), "v"(b));
    return r;
}

// ---------------- f32 -> bf16 streaming convert ----------------
__global__ __launch_bounds__(256)
void to_bf16(const float* __restrict__ in, short* __restrict__ outp, long n)
{
    long i0 = ((long)blockIdx.x * 256 + threadIdx.x) * 8;
    long stride = (long)gridDim.x * 256 * 8;
    for (long i = i0; i < n; i += stride) {
        f32x4 a = *(const f32x4*)(in + i);
        f32x4 b = *(const f32x4*)(in + i + 4);
        u32x4 o;
        o[0] = cvtpk(a[0], a[1]);
        o[1] = cvtpk(a[2], a[3]);
        o[2] = cvtpk(b[0], b[1]);
        o[3] = cvtpk(b[2], b[3]);
        *(u32x4*)(outp + i) = o;
    }
}

// ---------------- weight prep: W [nmat, K, 128] f32 -> WT [nmat, 128, K] bf16 ----------------
__global__ __launch_bounds__(256)
void prep_w(const float* __restrict__ W, short* __restrict__ WT, int K, int tot)
{
    int e = blockIdx.x * 256 + threadIdx.x;
    if (e >= tot) return;
    int mk = e >> 7;          // mi*K + k
    int n = e & 127;
    int mi = mk / K;
    int k = mk - mi * K;
    WT[(size_t)mi * K * 128 + (size_t)n * K + k] = f2b(W[e]);
}

// ---------------- weight-stationary message MLP (persistent blocks, bf16 X) ----------------
template<int NW>
__global__ __launch_bounds__(NW * 64, 1)
void mlp2_msg_ws(const short* __restrict__ Xb,
                 const short* __restrict__ W1T, const float* __restrict__ B1,
                 const short* __restrict__ W2T, const float* __restrict__ B2,
                 short* __restrict__ Z, size_t zstr, int M, int nChunks)
{
    constexpr int BM = NW * 32;
    constexpr int NT = NW * 64;
    __shared__ short sW1[128 * 136];
    __shared__ short sW2[128 * 136];
    __shared__ short sH[BM * 136];

    const int tid = threadIdx.x;
    const int lane = tid & 63;
    const int w = tid >> 6;
    const int p = lane & 15;
    const int q = lane >> 4;

    const int set = blockIdx.x & 1;
    const int c0 = blockIdx.x >> 1;
    const int cstr = gridDim.x >> 1;

    const short* w1g = W1T + set * 16384;
    const short* w2g = W2T + set * 16384;
    const float* b1g = B1 + set * 128;
    const float* b2g = B2 + set * 128;
    short* z = Z + (size_t)set * zstr;

    for (int e = tid * 8; e < 128 * 128; e += NT * 8) {
        int n = e >> 7, k = e & 127;
        *(short8*)(sW1 + n * 136 + k) = *(const short8*)(w1g + e);
        *(short8*)(sW2 + n * 136 + k) = *(const short8*)(w2g + e);
    }
    __syncthreads();

    if (c0 >= nChunks) return;

    short8 xfA[2][4], xfB[2][4];

    auto issueX = [&](short8 (&xf)[2][4], int c) {
        long base = (long)c * BM + w * 32;
        #pragma unroll
        for (int t = 0; t < 2; ++t) {
            long m = base + t * 16 + p;
            if (m > (long)M - 1) m = (long)M - 1;
            const short* src = Xb + m * 128 + q * 8;
            #pragma unroll
            for (int kk = 0; kk < 4; ++kk)
                xf[t][kk] = *(const short8*)(src + kk * 32);
        }
    };

    auto computeStore = [&](short8 (&xf)[2][4], int c) {
        long base = (long)c * BM + w * 32;
        // layer 1
        f32x4 acc[8][2];
        #pragma unroll
        for (int cc = 0; cc < 8; ++cc)
            #pragma unroll
            for (int t = 0; t < 2; ++t)
                acc[cc][t] = (f32x4){0.f, 0.f, 0.f, 0.f};

        #pragma unroll
        for (int kk = 0; kk < 4; ++kk) {
            short8 af[8];
            #pragma unroll
            for (int cc = 0; cc < 8; ++cc)
                af[cc] = *(const short8*)(sW1 + (cc * 16 + p) * 136 + kk * 32 + q * 8);
            #pragma unroll
            for (int cc = 0; cc < 8; ++cc)
                #pragma unroll
                for (int t = 0; t < 2; ++t)
                    acc[cc][t] = __builtin_amdgcn_mfma_f32_16x16x32_bf16(af[cc], xf[t][kk], acc[cc][t], 0, 0, 0);
        }

        #pragma unroll
        for (int cc = 0; cc < 8; ++cc) {
            f32x4 bb = *(const f32x4*)(b1g + cc * 16 + q * 4);
            #pragma unroll
            for (int t = 0; t < 2; ++t) {
                u32x2 u;
                u[0] = cvtpk(fmaxf(acc[cc][t][0] + bb[0], 0.f), fmaxf(acc[cc][t][1] + bb[1], 0.f));
                u[1] = cvtpk(fmaxf(acc[cc][t][2] + bb[2], 0.f), fmaxf(acc[cc][t][3] + bb[3], 0.f));
                *(u32x2*)(sH + (w * 32 + t * 16 + p) * 136 + cc * 16 + q * 4) = u;
            }
        }
        // wave-private sH: just drain this wave's LDS writes
        asm volatile("s_waitcnt lgkmcnt(0)" ::: "memory");

        // layer 2
        f32x4 acc2[8][2];
        #pragma unroll
        for (int cc = 0; cc < 8; ++cc)
            #pragma unroll
            for (int t = 0; t < 2; ++t)
                acc2[cc][t] = (f32x4){0.f, 0.f, 0.f, 0.f};

        #pragma unroll
        for (int kk = 0; kk < 4; ++kk) {
            short8 af[8], bfr[2];
            #pragma unroll
            for (int cc = 0; cc < 8; ++cc)
                af[cc] = *(const short8*)(sW2 + (cc * 16 + p) * 136 + kk * 32 + q * 8);
            #pragma unroll
            for (int t = 0; t < 2; ++t)
                bfr[t] = *(const short8*)(sH + (w * 32 + t * 16 + p) * 136 + kk * 32 + q * 8);
            #pragma unroll
            for (int cc = 0; cc < 8; ++cc)
                #pragma unroll
                for (int t = 0; t < 2; ++t)
                    acc2[cc][t] = __builtin_amdgcn_mfma_f32_16x16x32_bf16(af[cc], bfr[t], acc2[cc][t], 0, 0, 0);
        }

        #pragma unroll
        for (int cc = 0; cc < 8; ++cc) {
            f32x4 bb = *(const f32x4*)(b2g + cc * 16 + q * 4);
            #pragma unroll
            for (int t = 0; t < 2; ++t) {
                long m = base + t * 16 + p;
                if (m < M) {
                    u32x2 u;
                    u[0] = cvtpk(fmaxf(acc2[cc][t][0] + bb[0], 0.f), fmaxf(acc2[cc][t][1] + bb[1], 0.f));
                    u[1] = cvtpk(fmaxf(acc2[cc][t][2] + bb[2], 0.f), fmaxf(acc2[cc][t][3] + bb[3], 0.f));
                    *(u32x2*)(z + m * 128 + cc * 16 + q * 4) = u;
                }
            }
        }
    };

    int c = c0;
    issueX(xfA, c);
    while (true) {
        if (c + cstr < nChunks) issueX(xfB, c + cstr);
        computeStore(xfA, c);
        c += cstr; if (c >= nChunks) break;
        if (c + cstr < nChunks) issueX(xfA, c + cstr);
        computeStore(xfB, c);
        c += cstr; if (c >= nChunks) break;
    }
}

// ---------------- weight-stationary update MLP: X = concat(h bf16, m bf16), K1=256 ----------------
template<int NW>
__global__ __launch_bounds__(NW * 64, 1)
void mlp2_upd_ws(const short* __restrict__ Xb, const short* __restrict__ X2,
                 const short* __restrict__ W1T, const float* __restrict__ B1,
                 const short* __restrict__ W2T, const float* __restrict__ B2,
                 float* __restrict__ Out, int M, int nChunks)
{
    constexpr int BM = NW * 32;
    constexpr int NT = NW * 64;
    __shared__ short sW1[128 * 264];   // K=256, pad 8
    __shared__ short sW2[128 * 136];
    __shared__ short sH[BM * 136];

    const int tid = threadIdx.x;
    const int lane = tid & 63;
    const int w = tid >> 6;
    const int p = lane & 15;
    const int q = lane >> 4;

    const int c0 = blockIdx.x;
    const int cstr = gridDim.x;

    for (int e = tid * 8; e < 128 * 256; e += NT * 8) {
        int n = e >> 8, k = e & 255;
        *(short8*)(sW1 + n * 264 + k) = *(const short8*)(W1T + e);
    }
    for (int e = tid * 8; e < 128 * 128; e += NT * 8) {
        int n = e >> 7, k = e & 127;
        *(short8*)(sW2 + n * 136 + k) = *(const short8*)(W2T + e);
    }
    __syncthreads();

    if (c0 >= nChunks) return;

    short8 bufA[2][8], bufB[2][8];   // [t][kk] over K=256

    auto issueX = [&](short8 (&xf)[2][8], int c) {
        long base = (long)c * BM + w * 32;
        #pragma unroll
        for (int t = 0; t < 2; ++t) {
            long m = base + t * 16 + p;
            if (m > (long)M - 1) m = (long)M - 1;
            const short* s1 = Xb + m * 128 + q * 8;
            const short* s2 = X2 + m * 128 + q * 8;
            #pragma unroll
            for (int kk = 0; kk < 4; ++kk) {
                xf[t][kk]     = *(const short8*)(s1 + kk * 32);
                xf[t][kk + 4] = *(const short8*)(s2 + kk * 32);
            }
        }
    };

    auto computeStore = [&](short8 (&xf)[2][8], int c) {
        long base = (long)c * BM + w * 32;
        f32x4 acc[8][2];
        #pragma unroll
        for (int cc = 0; cc < 8; ++cc)
            #pragma unroll
            for (int t = 0; t < 2; ++t)
                acc[cc][t] = (f32x4){0.f, 0.f, 0.f, 0.f};

        #pragma unroll
        for (int kk = 0; kk < 8; ++kk) {
            short8 af[8];
            #pragma unroll
            for (int cc = 0; cc < 8; ++cc)
                af[cc] = *(const short8*)(sW1 + (cc * 16 + p) * 264 + kk * 32 + q * 8);
            #pragma unroll
            for (int cc = 0; cc < 8; ++cc)
                #pragma unroll
                for (int t = 0; t < 2; ++t)
                    acc[cc][t] = __builtin_amdgcn_mfma_f32_16x16x32_bf16(af[cc], xf[t][kk], acc[cc][t], 0, 0, 0);
        }

        #pragma unroll
        for (int cc = 0; cc < 8; ++cc) {
            f32x4 bb = *(const f32x4*)(B1 + cc * 16 + q * 4);
            #pragma unroll
            for (int t = 0; t < 2; ++t) {
                u32x2 u;
                u[0] = cvtpk(fmaxf(acc[cc][t][0] + bb[0], 0.f), fmaxf(acc[cc][t][1] + bb[1], 0.f));
                u[1] = cvtpk(fmaxf(acc[cc][t][2] + bb[2], 0.f), fmaxf(acc[cc][t][3] + bb[3], 0.f));
                *(u32x2*)(sH + (w * 32 + t * 16 + p) * 136 + cc * 16 + q * 4) = u;
            }
        }
        asm volatile("s_waitcnt lgkmcnt(0)" ::: "memory");

        f32x4 acc2[8][2];
        #pragma unroll
        for (int cc = 0; cc < 8; ++cc)
            #pragma unroll
            for (int t = 0; t < 2; ++t)
                acc2[cc][t] = (f32x4){0.f, 0.f, 0.f, 0.f};

        #pragma unroll
        for (int kk = 0; kk < 4; ++kk) {
            short8 af[8], bfr[2];
            #pragma unroll
            for (int cc = 0; cc < 8; ++cc)
                af[cc] = *(const short8*)(sW2 + (cc * 16 + p) * 136 + kk * 32 + q * 8);
            #pragma unroll
            for (int t = 0; t < 2; ++t)
                bfr[t] = *(const short8*)(sH + (w * 32 + t * 16 + p) * 136 + kk * 32 + q * 8);
            #pragma unroll
            for (int cc = 0; cc < 8; ++cc)
                #pragma unroll
                for (int t = 0; t < 2; ++t)
                    acc2[cc][t] = __builtin_amdgcn_mfma_f32_16x16x32_bf16(af[cc], bfr[t], acc2[cc][t], 0, 0, 0);
        }

        #pragma unroll
        for (int cc = 0; cc < 8; ++cc) {
            f32x4 bb = *(const f32x4*)(B2 + cc * 16 + q * 4);
            #pragma unroll
            for (int t = 0; t < 2; ++t) {
                long m = base + t * 16 + p;
                if (m < M) {
                    f32x4 fv;
                    #pragma unroll
                    for (int i = 0; i < 4; ++i)
                        fv[i] = fmaxf(acc2[cc][t][i] + bb[i], 0.f);
                    *(f32x4*)(Out + m * 128 + cc * 16 + q * 4) = fv;
                }
            }
        }
    };

    int c = c0;
    issueX(bufA, c);
    while (true) {
        if (c + cstr < nChunks) issueX(bufB, c + cstr);
        computeStore(bufA, c);
        c += cstr; if (c >= nChunks) break;
        if (c + cstr < nChunks) issueX(bufA, c + cstr);
        computeStore(bufB, c);
        c += cstr; if (c >= nChunks) break;
    }
}

// ---------------- CSR build ----------------

__global__ __launch_bounds__(256)
void hist_kernel(const int* __restrict__ rows, int* __restrict__ counts, int E)
{
    int e = blockIdx.x * 256 + threadIdx.x;
    if (e < E) atomicAdd(&counts[rows[e]], 1);
}

__global__ __launch_bounds__(256)
void seg_reduce(const int* __restrict__ counts, int* __restrict__ bsum, int N)
{
    __shared__ int s[256];
    int b = blockIdx.x, t = threadIdx.x;
    int base = b * 512;
    int v = 0;
    if (base + t < N) v += counts[base + t];
    if (base + 256 + t < N) v += counts[base + 256 + t];
    s[t] = v;
    __syncthreads();
    for (int off = 128; off > 0; off >>= 1) {
        if (t < off) s[t] += s[t + off];
        __syncthreads();
    }
    if (t == 0) bsum[b] = s[0];
}

__global__ __launch_bounds__(1024)
void scan_bsum(int* __restrict__ bsum, int B)
{
    __shared__ int s[1024];
    int t = threadIdx.x;
    s[t] = (t < B) ? bsum[t] : 0;
    __syncthreads();
    for (int off = 1; off < 1024; off <<= 1) {
        int v = (t >= off) ? s[t - off] : 0;
        __syncthreads();
        s[t] += v;
        __syncthreads();
    }
    if (t < B) bsum[t] = (t == 0) ? 0 : s[t - 1];
}

__global__ __launch_bounds__(512)
void scan_final(const int* __restrict__ counts, const int* __restrict__ bsum,
                int* __restrict__ offs, int N)
{
    __shared__ int s[512];
    int b = blockIdx.x, t = threadIdx.x;
    int idx = b * 512 + t;
    int c = (idx < N) ? counts[idx] : 0;
    s[t] = c;
    __syncthreads();
    for (int off = 1; off < 512; off <<= 1) {
        int v = (t >= off) ? s[t - off] : 0;
        __syncthreads();
        s[t] += v;
        __syncthreads();
    }
    if (idx < N) offs[idx] = bsum[b] + s[t] - c;
    if (idx == N - 1) offs[N] = bsum[b] + s[t];
}

__global__ __launch_bounds__(256)
void csr_fill(const int* __restrict__ rows, const int* __restrict__ cols,
              const int* __restrict__ offs, int* __restrict__ cursor,
              int* __restrict__ edgeCol, int E)
{
    int e = blockIdx.x * 256 + threadIdx.x;
    if (e >= E) return;
    int r = rows[e];
    int pos = offs[r] + atomicAdd(&cursor[r], 1);
    edgeCol[pos] = cols[e];
}

// 16 lanes per row (each lane: 8 features = 16B load), 4 rows per wave, 4-edge unroll
__global__ __launch_bounds__(256)
void csr_gather4(const short* __restrict__ z, const int* __restrict__ offs,
                 const int* __restrict__ edgeCol, short* __restrict__ m, int N)
{
    int wid = (int)((blockIdx.x * 256 + threadIdx.x) >> 6);
    int lane = threadIdx.x & 63;
    int sub = lane >> 4;       // 0..3: row within wave
    int sl = lane & 15;        // 0..15: 16B slice within row
    int row = wid * 4 + sub;
    if (row >= N) return;
    int beg = offs[row], end = offs[row + 1];

    float a[8];
    #pragma unroll
    for (int i = 0; i < 8; ++i) a[i] = 0.f;

    int j = beg;
    for (; j + 3 < end; j += 4) {
        int c0 = edgeCol[j], c1 = edgeCol[j + 1], c2 = edgeCol[j + 2], c3 = edgeCol[j + 3];
        short8 v0 = *(const short8*)(z + (long)c0 * 128 + sl * 8);
        short8 v1 = *(const short8*)(z + (long)c1 * 128 + sl * 8);
        short8 v2 = *(const short8*)(z + (long)c2 * 128 + sl * 8);
        short8 v3 = *(const short8*)(z + (long)c3 * 128 + sl * 8);
        #pragma unroll
        for (int i = 0; i < 8; ++i)
            a[i] += (b2f(v0[i]) + b2f(v1[i])) + (b2f(v2[i]) + b2f(v3[i]));
    }
    for (; j < end; ++j) {
        int c = edgeCol[j];
        short8 v = *(const short8*)(z + (long)c * 128 + sl * 8);
        #pragma unroll
        for (int i = 0; i < 8; ++i) a[i] += b2f(v[i]);
    }

    u32x4 o;
    o[0] = cvtpk(a[0], a[1]);
    o[1] = cvtpk(a[2], a[3]);
    o[2] = cvtpk(a[4], a[5]);
    o[3] = cvtpk(a[6], a[7]);
    *(u32x4*)(m + (long)row * 128 + sl * 8) = o;
}

extern "C" void kernel_launch(void* const* d_in, const int* in_sizes, int n_in,
                              void* d_out, int out_size, void* d_ws, size_t ws_size,
                              hipStream_t stream)
{
    const float* hv   = (const float*)d_in[0];
    const float* hc   = (const float*)d_in[1];
    const int* row_v  = (const int*)d_in[2];
    const int* col_v  = (const int*)d_in[3];
    const int* row_c  = (const int*)d_in[4];
    const int* col_c  = (const int*)d_in[5];
    const float* mw1  = (const float*)d_in[6];
    const float* mb1  = (const float*)d_in[7];
    const float* mw2  = (const float*)d_in[8];
    const float* mb2  = (const float*)d_in[9];
    const float* uw1  = (const float*)d_in[10];
    const float* ub1  = (const float*)d_in[11];
    const float* uw2  = (const float*)d_in[12];
    const float* ub2  = (const float*)d_in[13];
    float* out = (float*)d_out;

    // ws: zv bf16[2NC,128] | zc bf16[2NV,128] | mv bf16[NV,128] | mc bf16[NC,128]
    //     | WT bf16 | hvb bf16[NV,128] | hcb bf16[NC,128] | int scratch
    short* zv = (short*)d_ws;
    short* zc = zv + (size_t)2 * NCC * 128;
    short* mv = zc + (size_t)2 * NVV * 128;
    short* mc = mv + (size_t)NVV * 128;
    short* wt_m1 = mc + (size_t)NCC * 128;      // 4 * 16384
    short* wt_m2 = wt_m1 + 4 * 16384;           // 4 * 16384
    short* wt_u1 = wt_m2 + 4 * 16384;           // 2 * 32768
    short* wt_u2 = wt_u1 + 2 * 32768;           // 2 * 16384
    short* hvb = wt_u2 + 2 * 16384;
    short* hcb = hvb + (size_t)NVV * 128;
    int* edge_v = (int*)(hcb + (size_t)NCC * 128);
    int* edge_c = edge_v + NEE;
    int* offs_v = edge_c + NEE;
    int* offs_c = offs_v + (NVV + 1);
    int* cnt_v  = offs_c + (NCC + 1);
    int* cnt_c  = cnt_v + NVV;
    int* bsum_v = cnt_c + NCC;
    int* bsum_c = bsum_v + 1024;

    const int Bv = (NVV + 511) / 512;   // 196
    const int Bc = (NCC + 511) / 512;   // 782

    // ---- weight prep + input bf16 conversion
    prep_w<<<(4 * 16384 + 255) / 256, 256, 0, stream>>>(mw1, wt_m1, 128, 4 * 16384);
    prep_w<<<(4 * 16384 + 255) / 256, 256, 0, stream>>>(mw2, wt_m2, 128, 4 * 16384);
    prep_w<<<(2 * 32768 + 255) / 256, 256, 0, stream>>>(uw1, wt_u1, 256, 2 * 32768);
    prep_w<<<(2 * 16384 + 255) / 256, 256, 0, stream>>>(uw2, wt_u2, 128, 2 * 16384);
    to_bf16<<<2048, 256, 0, stream>>>(hv, hvb, (long)NVV * 128);
    to_bf16<<<2048, 256, 0, stream>>>(hc, hcb, (long)NCC * 128);

    // ---- CSR build (both graphs)
    hipMemsetAsync(cnt_v, 0, NVV * sizeof(int), stream);
    hipMemsetAsync(cnt_c, 0, NCC * sizeof(int), stream);
    hist_kernel<<<(NEE + 255) / 256, 256, 0, stream>>>(row_v, cnt_v, NEE);
    hist_kernel<<<(NEE + 255) / 256, 256, 0, stream>>>(row_c, cnt_c, NEE);
    seg_reduce<<<Bv, 256, 0, stream>>>(cnt_v, bsum_v, NVV);
    seg_reduce<<<Bc, 256, 0, stream>>>(cnt_c, bsum_c, NCC);
    scan_bsum<<<1, 1024, 0, stream>>>(bsum_v, Bv);
    scan_bsum<<<1, 1024, 0, stream>>>(bsum_c, Bc);
    scan_final<<<Bv, 512, 0, stream>>>(cnt_v, bsum_v, offs_v, NVV);
    scan_final<<<Bc, 512, 0, stream>>>(cnt_c, bsum_c, offs_c, NCC);
    hipMemsetAsync(cnt_v, 0, NVV * sizeof(int), stream);
    hipMemsetAsync(cnt_c, 0, NCC * sizeof(int), stream);
    csr_fill<<<(NEE + 255) / 256, 256, 0, stream>>>(row_v, col_v, offs_v, cnt_v, edge_v, NEE);
    csr_fill<<<(NEE + 255) / 256, 256, 0, stream>>>(row_c, col_c, offs_c, cnt_c, edge_c, NEE);

    // ---- message MLPs (weight-stationary persistent; set = blockIdx&1)
    mlp2_msg_ws<8><<<256, 512, 0, stream>>>(
        hcb, wt_m1, mb1, wt_m2, mb2, zv, (size_t)NCC * 128, NCC, (NCC + 255) / 256);
    mlp2_msg_ws<8><<<256, 512, 0, stream>>>(
        hvb, wt_m1 + 2 * 16384, mb1 + 2 * 128, wt_m2 + 2 * 16384, mb2 + 2 * 128,
        zc, (size_t)NVV * 128, NVV, (NVV + 255) / 256);

    // ---- segment sums via CSR gather (4 rows/wave, 16B loads)
    csr_gather4<<<(NVV + 15) / 16, 256, 0, stream>>>(zv, offs_v, edge_v, mv, NVV);
    csr_gather4<<<(NCC + 15) / 16, 256, 0, stream>>>(zc, offs_c, edge_c, mc, NCC);

    // ---- update MLPs: concat(h, m) -> K1=256
    mlp2_upd_ws<6><<<256, 384, 0, stream>>>(
        hvb, mv, wt_u1, ub1, wt_u2, ub2, out, NVV, (NVV + 191) / 192);
    mlp2_upd_ws<6><<<256, 384, 0, stream>>>(
        hcb, mc, wt_u1 + 32768, ub1 + 128, wt_u2 + 16384, ub2 + 128,
        out + (size_t)NVV * 128, NCC, (NCC + 191) / 192);
}